// Round 5
// baseline (857.482 us; speedup 1.0000x reference)
//
#include <hip/hip_runtime.h>

typedef short bfx8 __attribute__((ext_vector_type(8)));
typedef float fx4 __attribute__((ext_vector_type(4)));

#define E_TILE 128

__device__ __forceinline__ short f2b(float f) {
  union { float f; unsigned u; } v; v.f = f;
  unsigned u = v.u;
  u += 0x7fffu + ((u >> 16) & 1u);   // RNE
  return (short)(u >> 16);
}
__device__ __forceinline__ float relu(float f) { return f > 0.f ? f : 0.f; }
__device__ __forceinline__ float asf(unsigned u) { union { unsigned u; float f; } v; v.u = u; return v.f; }
__device__ __forceinline__ unsigned asu(float f) { union { float f; unsigned u; } v; v.f = f; return v.u; }

// ---------------- prep: convert weights to bf16 in ws ----------------
// B1[n][k], n in [0,512): n<256 -> W1[n][k] (P part); n>=256 -> W1[n-256][256+k] (Q part)
__global__ void k_prep(const float* __restrict__ W1, const float* __restrict__ W2,
                       unsigned short* __restrict__ B1, unsigned short* __restrict__ W2b) {
  int t = blockIdx.x * 256 + threadIdx.x;
  if (t < 512 * 256) {
    int n = t >> 8, k = t & 255;
    float v = (n < 256) ? W1[n * 512 + k] : W1[(n - 256) * 512 + 256 + k];
    B1[t] = (unsigned short)f2b(v);
  } else if (t < 512 * 256 + 256 * 256) {
    int i = t - 512 * 256;
    W2b[i] = (unsigned short)f2b(W2[i]);
  }
}

// ---------------- convert x fp32 -> bf16 (streaming, halves k_node read) ------
__global__ __launch_bounds__(256) void k_convert(const float* __restrict__ x,
                                                 unsigned short* __restrict__ xb, int n) {
  int i = (blockIdx.x * 256 + threadIdx.x) * 8;
  if (i < n) {
    float4 a = *(const float4*)(x + i);
    float4 b = *(const float4*)(x + i + 4);
    bfx8 o;
    o[0] = f2b(a.x); o[1] = f2b(a.y); o[2] = f2b(a.z); o[3] = f2b(a.w);
    o[4] = f2b(b.x); o[5] = f2b(b.y); o[6] = f2b(b.z); o[7] = f2b(b.w);
    *(bfx8*)(xb + i) = o;
  }
}

// ---------------- node kernel: PQ[m][0:512] = x[m] @ B1^T (bf16 out) ----------------
// Barrier-free main loop: A-frags straight from global xb (64 rows/block ->
// L1-hot after first ks; 8 waves share them), B-frags straight from global B1
// (256 KB total -> L2-hot). No LDS staging => waves free-run; only the
// store-transpose epilogue synchronizes. ~105 regs -> no spill at the
// (512,4) 128-reg cap, 2 blocks/CU (16 waves, 50%).
// Q half (cols 256..511) gets b1 folded in: Q' = Q + b1.
template <bool USE_XB>
__launch_bounds__(512, 4)
__global__ void k_node(const float* __restrict__ x, const unsigned short* __restrict__ xb,
                       const unsigned short* __restrict__ B1, const float* __restrict__ b1,
                       unsigned short* __restrict__ PQ, int n_nodes) {
  __shared__ __align__(16) short smT[32 * 520];   // 33.3 KB transpose buffer
  const int tid = threadIdx.x;
  const int wave = tid >> 6, lane = tid & 63;
  const int lr = lane & 15, lg = lane >> 4;
  const int m0 = blockIdx.x * 64;
  const int n0 = wave * 64;

  // tail rows clamp to a valid row (computed but never stored)
  int mrow[4];
#pragma unroll
  for (int mt = 0; mt < 4; ++mt) {
    int m = m0 + mt * 16 + lr;
    mrow[mt] = m < n_nodes ? m : (n_nodes - 1);
  }

  fx4 acc[4][4] = {};

#pragma unroll 2
  for (int ks = 0; ks < 8; ++ks) {
    bfx8 af[4];
#pragma unroll
    for (int mt = 0; mt < 4; ++mt) {
      if (USE_XB) {
        af[mt] = *(const bfx8*)(xb + (size_t)mrow[mt] * 256 + ks * 32 + lg * 8);
      } else {
        const float* p = x + (size_t)mrow[mt] * 256 + ks * 32 + lg * 8;
        float4 v0 = *(const float4*)(p);
        float4 v1 = *(const float4*)(p + 4);
        bfx8 o;
        o[0] = f2b(v0.x); o[1] = f2b(v0.y); o[2] = f2b(v0.z); o[3] = f2b(v0.w);
        o[4] = f2b(v1.x); o[5] = f2b(v1.y); o[6] = f2b(v1.z); o[7] = f2b(v1.w);
        af[mt] = o;
      }
    }
#pragma unroll
    for (int nt = 0; nt < 4; ++nt) {
      bfx8 bf = *(const bfx8*)(B1 + (size_t)(n0 + nt * 16 + lr) * 256 + ks * 32 + lg * 8);
#pragma unroll
      for (int mt = 0; mt < 4; ++mt)
        acc[mt][nt] = __builtin_amdgcn_mfma_f32_16x16x32_bf16(af[mt], bf, acc[mt][nt], 0, 0, 0);
    }
  }

  // per-lane output-column bias: 0 for P cols, b1[n-256] for Q' cols
  float bias[4];
#pragma unroll
  for (int nt = 0; nt < 4; ++nt) {
    int n = n0 + nt * 16 + lr;
    bias[nt] = (n >= 256) ? b1[n - 256] : 0.f;
  }

  // epilogue: two half-passes (rows 0-31, 32-63) through smT, coalesced stores.
  // All loops fully unrolled: acc[] must stay statically indexed (round-1 spill).
#pragma unroll
  for (int h = 0; h < 2; ++h) {
#pragma unroll
    for (int mt2 = 0; mt2 < 2; ++mt2) {
      const int mt = 2 * h + mt2;
#pragma unroll
      for (int nt = 0; nt < 4; ++nt)
#pragma unroll
        for (int i = 0; i < 4; ++i) {
          int mr = mt2 * 16 + lg * 4 + i;
          int n = n0 + nt * 16 + lr;
          smT[mr * 520 + n] = f2b(acc[mt][nt][i] + bias[nt]);
        }
    }
    __syncthreads();
    int r = tid >> 4, cbase = (tid & 15) * 8;
    int m = m0 + h * 32 + r;
    if (m < n_nodes) {
#pragma unroll
      for (int j = 0; j < 4; ++j) {
        int c = cbase + j * 128;
        *(bfx8*)(PQ + (size_t)m * 512 + c) = *(const bfx8*)&smT[r * 520 + c];
      }
    }
    __syncthreads();
  }
}

// ---------------- edge kernel: h1=relu(P[src]+Q'[dst]); h2=relu(h1@W2^T+b2); out=h2@w3+b3 --
// 1024 threads / 16 waves; wave w owns n in [w*16, w*16+16): bw[8]=32 VGPR +
// acc[8]=32 AGPR + temps ~100 regs. A 16-wave block REQUIRES <=128 regs
// (4 waves/EU) - fits with margin, so no spill (rounds 3/4: 64-85 MB of spill
// writes from over-cap register demand erased the occupancy gain).
// E_TILE=128 -> 8x16B gather loads/thread for memory-level parallelism.
__launch_bounds__(1024, 4)
__global__ void k_edge(const unsigned short* __restrict__ PQ,
                       const int* __restrict__ src, const int* __restrict__ dst,
                       const unsigned short* __restrict__ W2b,
                       const float* __restrict__ b2, const float* __restrict__ W3,
                       const float* __restrict__ b3, float* __restrict__ out,
                       int E, int ntiles) {
  __shared__ __align__(16) short smH[E_TILE * 264];  // 67.6 KB, stride 264
  __shared__ float smS[16][E_TILE];                  // 8 KB
  const int tid = threadIdx.x;
  const int wave = tid >> 6, lane = tid & 63;
  const int lr = lane & 15, lg = lane >> 4;

  // W2 fragments: this wave's 16 N rows, full K=256 (8 k-steps)
  bfx8 bw[8];
  float b2v, w3v;
  {
    int n = wave * 16 + lr;
    b2v = b2[n];
    w3v = W3[n];
#pragma unroll
    for (int ks = 0; ks < 8; ++ks)
      bw[ks] = *(const bfx8*)(W2b + (size_t)n * 256 + ks * 32 + lg * 8);
  }
  const float b3v = b3[0];

  const int r = tid >> 3;            // edge row in tile (8 thr/edge)
  const int sub = tid & 7;
  const int stride = gridDim.x * E_TILE;

  // prefetch first tile's indices
  int e0 = blockIdx.x * E_TILE + r;
  int s_cur = 0, d_cur = 0;
  if (e0 < E) { s_cur = src[e0]; d_cur = dst[e0]; }

  for (int tile = blockIdx.x; tile < ntiles; tile += gridDim.x) {
    const int base = tile * E_TILE;
    const int e = base + r;
    // gather + fuse layer1: h1 = relu(P[src]+Q'[dst]) -> smH bf16.
    // bf16 pairs as u32: shl/and extract, round-half-up pack via +0x8000+perm.
    if (e < E) {
      const unsigned* ps = (const unsigned*)(PQ + (size_t)s_cur * 512);
      const unsigned* pd = (const unsigned*)(PQ + (size_t)d_cur * 512 + 256);
#pragma unroll
      for (int it = 0; it < 4; ++it) {
        int c = sub * 8 + it * 64;
        uint4 pv = *(const uint4*)(ps + (c >> 1));
        uint4 qv = *(const uint4*)(pd + (c >> 1));
        unsigned o[4];
        const unsigned* pw = (const unsigned*)&pv;
        const unsigned* qw = (const unsigned*)&qv;
#pragma unroll
        for (int w = 0; w < 4; ++w) {
          unsigned up = pw[w], uq = qw[w];
          float slo = relu(asf(up << 16) + asf(uq << 16));
          float shi = relu(asf(up & 0xffff0000u) + asf(uq & 0xffff0000u));
          o[w] = __builtin_amdgcn_perm(asu(shi) + 0x8000u, asu(slo) + 0x8000u,
                                       0x07060302u);
        }
        *(uint4*)&smH[r * 264 + c] = make_uint4(o[0], o[1], o[2], o[3]);
      }
    } else {
#pragma unroll
      for (int it = 0; it < 4; ++it) {
        int c = sub * 8 + it * 64;
        *(uint4*)&smH[r * 264 + c] = make_uint4(0, 0, 0, 0);
      }
    }
    // issue next tile's index loads (overlap with barrier + MFMA)
    int e_next = e + stride;
    if (e_next < E) { s_cur = src[e_next]; d_cur = dst[e_next]; }
    __syncthreads();

    // layer2 GEMM: 128M x 16N per wave, K=256
    fx4 acc[8];
#pragma unroll
    for (int mt = 0; mt < 8; ++mt) acc[mt] = (fx4){0.f, 0.f, 0.f, 0.f};
#pragma unroll 1
    for (int ks = 0; ks < 8; ++ks) {
#pragma unroll
      for (int mt = 0; mt < 8; ++mt) {
        bfx8 af = *(const bfx8*)&smH[(mt * 16 + lr) * 264 + ks * 32 + lg * 8];
        acc[mt] = __builtin_amdgcn_mfma_f32_16x16x32_bf16(af, bw[ks], acc[mt], 0, 0, 0);
      }
    }

    // epilogue: relu(acc+b2)*w3, shfl-reduce over this wave's 16 cols
#pragma unroll
    for (int mt = 0; mt < 8; ++mt)
#pragma unroll
      for (int i = 0; i < 4; ++i) {
        float p = relu(acc[mt][i] + b2v) * w3v;
        p += __shfl_xor(p, 1);
        p += __shfl_xor(p, 2);
        p += __shfl_xor(p, 4);
        p += __shfl_xor(p, 8);
        if (lr == 0) smS[wave][mt * 16 + lg * 4 + i] = p;
      }
    __syncthreads();
    if (tid < E_TILE) {
      int eo = base + tid;
      if (eo < E) {
        float s = b3v;
#pragma unroll
        for (int w = 0; w < 16; ++w) s += smS[w][tid];
        out[eo] = s;
      }
    }
    __syncthreads();
  }
}

// ---------------- fallback (if ws too small): naive fp32, 1 edge per wave ----------------
__global__ void k_fallback(const float* __restrict__ x, const int* __restrict__ src,
                           const int* __restrict__ dst, const float* __restrict__ W1,
                           const float* __restrict__ b1, const float* __restrict__ W2,
                           const float* __restrict__ b2, const float* __restrict__ W3,
                           const float* __restrict__ b3, float* __restrict__ out, int E) {
  __shared__ float smF[4][512];
  __shared__ float smG[4][256];
  int wave = threadIdx.x >> 6, lane = threadIdx.x & 63;
  int e = blockIdx.x * 4 + wave;
  bool valid = e < E;
  int ec = valid ? e : 0;
  int s = src[ec], d = dst[ec];
  for (int j = 0; j < 8; ++j) {
    int k = lane * 8 + j;
    smF[wave][k] = (k < 256) ? x[(size_t)s * 256 + k] : x[(size_t)d * 256 + k - 256];
  }
  __syncthreads();
  for (int t = 0; t < 4; ++t) {
    int n = lane + t * 64;
    float a = b1[n];
    for (int k = 0; k < 512; ++k) a += smF[wave][k] * W1[n * 512 + k];
    smG[wave][n] = relu(a);
  }
  __syncthreads();
  float p = 0.f;
  for (int t = 0; t < 4; ++t) {
    int n = lane + t * 64;
    float a = b2[n];
    for (int k = 0; k < 256; ++k) a += smG[wave][k] * W2[n * 256 + k];
    p += relu(a) * W3[n];
  }
  for (int m = 1; m < 64; m <<= 1) p += __shfl_xor(p, m);
  if (lane == 0 && valid) out[e] = p + b3[0];
}

extern "C" void kernel_launch(void* const* d_in, const int* in_sizes, int n_in,
                              void* d_out, int out_size, void* d_ws, size_t ws_size,
                              hipStream_t stream) {
  const float* x  = (const float*)d_in[0];
  const int*   src = (const int*)d_in[1];
  const int*   dst = (const int*)d_in[2];
  const float* W1 = (const float*)d_in[3];
  const float* b1 = (const float*)d_in[4];
  const float* W2 = (const float*)d_in[5];
  const float* b2 = (const float*)d_in[6];
  const float* W3 = (const float*)d_in[7];
  const float* b3 = (const float*)d_in[8];
  float* out = (float*)d_out;

  const int E = in_sizes[1];
  const int n_nodes = in_sizes[0] / 256;
  const int n_x = in_sizes[0];

  const size_t offB1 = 0;
  const size_t offW2 = (size_t)512 * 256 * 2;                  // 262144
  const size_t offXB = offW2 + (size_t)256 * 256 * 2;          // 393216
  const size_t offPQ = offXB + (size_t)n_x * 2;                // + 25.6 MB
  const size_t need_full = offPQ + (size_t)n_nodes * 512 * 2;  // ~77.2 MB
  const size_t offPQ2 = offXB;                                 // no-xb layout
  const size_t need_noxb = offPQ2 + (size_t)n_nodes * 512 * 2; // ~51.6 MB

  const int ntiles = (E + E_TILE - 1) / E_TILE;
  const int egrid = ntiles < 256 ? ntiles : 256;   // 1 block/CU resident

  if (ws_size >= need_full) {
    unsigned short* B1  = (unsigned short*)((char*)d_ws + offB1);
    unsigned short* W2b = (unsigned short*)((char*)d_ws + offW2);
    unsigned short* xb  = (unsigned short*)((char*)d_ws + offXB);
    unsigned short* PQ  = (unsigned short*)((char*)d_ws + offPQ);
    k_prep<<<768, 256, 0, stream>>>(W1, W2, B1, W2b);
    k_convert<<<(n_x + 2047) / 2048, 256, 0, stream>>>(x, xb, n_x);
    k_node<true><<<(n_nodes + 63) / 64, 512, 0, stream>>>(x, xb, B1, b1, PQ, n_nodes);
    k_edge<<<egrid, 1024, 0, stream>>>(PQ, src, dst, W2b, b2, W3, b3, out, E, ntiles);
  } else if (ws_size >= need_noxb) {
    unsigned short* B1  = (unsigned short*)((char*)d_ws + offB1);
    unsigned short* W2b = (unsigned short*)((char*)d_ws + offW2);
    unsigned short* PQ  = (unsigned short*)((char*)d_ws + offPQ2);
    k_prep<<<768, 256, 0, stream>>>(W1, W2, B1, W2b);
    k_node<false><<<(n_nodes + 63) / 64, 512, 0, stream>>>(x, nullptr, B1, b1, PQ, n_nodes);
    k_edge<<<egrid, 1024, 0, stream>>>(PQ, src, dst, W2b, b2, W3, b3, out, E, ntiles);
  } else {
    k_fallback<<<(E + 3) / 4, 256, 0, stream>>>(x, src, dst, W1, b1, W2, b2, W3, b3, out, E);
  }
}

// Round 6
// 219.673 us; speedup vs baseline: 3.9035x; 3.9035x over previous
//
#include <hip/hip_runtime.h>

typedef short bfx8 __attribute__((ext_vector_type(8)));
typedef float fx4 __attribute__((ext_vector_type(4)));

#define E_TILE 64

__device__ __forceinline__ float b2f(short s) {
  union { unsigned u; float f; } v; v.u = ((unsigned)(unsigned short)s) << 16; return v.f;
}
__device__ __forceinline__ short f2b(float f) {
  union { float f; unsigned u; } v; v.f = f;
  unsigned u = v.u;
  u += 0x7fffu + ((u >> 16) & 1u);   // RNE
  return (short)(u >> 16);
}
__device__ __forceinline__ float relu(float f) { return f > 0.f ? f : 0.f; }

// ---------------- prep: convert weights to bf16 in ws ----------------
// B1[n][k], n in [0,512): n<256 -> W1[n][k] (P part); n>=256 -> W1[n-256][256+k] (Q part)
__global__ void k_prep(const float* __restrict__ W1, const float* __restrict__ W2,
                       unsigned short* __restrict__ B1, unsigned short* __restrict__ W2b) {
  int t = blockIdx.x * 256 + threadIdx.x;
  if (t < 512 * 256) {
    int n = t >> 8, k = t & 255;
    float v = (n < 256) ? W1[n * 512 + k] : W1[(n - 256) * 512 + 256 + k];
    B1[t] = (unsigned short)f2b(v);
  } else if (t < 512 * 256 + 256 * 256) {
    int i = t - 512 * 256;
    W2b[i] = (unsigned short)f2b(W2[i]);
  }
}

// ---------------- node kernel: PQ[m][0:512] = x[m] @ B1^T (bf16), b1 folded into Q half ---
// Low-pressure design: A-tile (64 rows x 256 K, bf16) staged in LDS ONCE per
// block (fp32->bf16 converted in-register), then NO barriers in the compute
// loop. B1 fragments read straight from global (256 KB total -> L2-hot; each
// block reads B1 once = 200 MB L2 traffic chip-wide). Two sequential N-half
// passes (P cols then Q cols) keep acc at 64 AGPR; total regs ~115 -> no cap,
// no spill. LDS 50.7 KB -> 2-3 blocks/CU.
__launch_bounds__(256, 2)
__global__ void k_node(const float* __restrict__ x, const unsigned short* __restrict__ B1,
                       const float* __restrict__ b1,
                       unsigned short* __restrict__ PQ, int n_nodes) {
  __shared__ __align__(16) short smA[64 * 264];   // 33.8 KB, element stride 264 (16B-aligned)
  __shared__ __align__(16) short smT[32 * 264];   // 16.9 KB transpose buffer
  const int tid = threadIdx.x;
  const int wave = tid >> 6, lane = tid & 63;
  const int lr = lane & 15, lg = lane >> 4;
  const int m0 = blockIdx.x * 64;

  // ---- stage A once: 64 rows x 256 cols fp32 -> bf16 ----
  {
    int r = tid >> 2;
    int m = m0 + r;
    bool ok = m < n_nodes;
#pragma unroll
    for (int j = 0; j < 8; ++j) {
      int c = (tid & 3) * 8 + j * 32;
      bfx8 o;
      if (ok) {
        const float* p = x + (size_t)m * 256 + c;
        float4 v0 = *(const float4*)(p);
        float4 v1 = *(const float4*)(p + 4);
        o[0] = f2b(v0.x); o[1] = f2b(v0.y); o[2] = f2b(v0.z); o[3] = f2b(v0.w);
        o[4] = f2b(v1.x); o[5] = f2b(v1.y); o[6] = f2b(v1.z); o[7] = f2b(v1.w);
      } else {
        o = (bfx8){0, 0, 0, 0, 0, 0, 0, 0};
      }
      *(bfx8*)&smA[r * 264 + c] = o;
    }
  }
  __syncthreads();

  // ---- two N-half passes: half 0 -> P (B1 rows 0..255), half 1 -> Q' (256..511) ----
#pragma unroll
  for (int half = 0; half < 2; ++half) {
    const int n0 = half * 256 + wave * 64;

    fx4 acc[4][4] = {};
#pragma unroll
    for (int ks = 0; ks < 8; ++ks) {
      bfx8 af[4];
#pragma unroll
      for (int mt = 0; mt < 4; ++mt)
        af[mt] = *(const bfx8*)&smA[(mt * 16 + lr) * 264 + ks * 32 + lg * 8];
#pragma unroll
      for (int nt = 0; nt < 4; ++nt) {
        bfx8 bf = *(const bfx8*)(B1 + (size_t)(n0 + nt * 16 + lr) * 256 + ks * 32 + lg * 8);
#pragma unroll
        for (int mt = 0; mt < 4; ++mt)
          acc[mt][nt] = __builtin_amdgcn_mfma_f32_16x16x32_bf16(af[mt], bf, acc[mt][nt], 0, 0, 0);
      }
    }

    // bias: 0 for P half, b1[n-256] for Q' half
    float bias[4];
#pragma unroll
    for (int nt = 0; nt < 4; ++nt) {
      int n = n0 + nt * 16 + lr;
      bias[nt] = half ? b1[n - 256] : 0.f;
    }

    // epilogue: two 32-row passes through smT, coalesced half-row stores.
    // Fully unrolled: acc[] must stay statically indexed (round-1 spill lesson).
#pragma unroll
    for (int h = 0; h < 2; ++h) {
      __syncthreads();                 // smT reuse boundary
#pragma unroll
      for (int mt2 = 0; mt2 < 2; ++mt2) {
        const int mt = 2 * h + mt2;
#pragma unroll
        for (int nt = 0; nt < 4; ++nt)
#pragma unroll
          for (int i = 0; i < 4; ++i) {
            int mr = mt2 * 16 + lg * 4 + i;
            int nc = wave * 64 + nt * 16 + lr;   // 0..255 within half
            smT[mr * 264 + nc] = f2b(acc[mt][nt][i] + bias[nt]);
          }
      }
      __syncthreads();
      int r = tid >> 3, cbase = (tid & 7) * 8;
      int m = m0 + h * 32 + r;
      if (m < n_nodes) {
#pragma unroll
        for (int j = 0; j < 4; ++j) {
          int c = cbase + j * 64;
          *(bfx8*)(PQ + (size_t)m * 512 + half * 256 + c) = *(const bfx8*)&smT[r * 264 + c];
        }
      }
    }
  }
}

// ---------------- edge kernel (round-2 proven structure): ----------------
// h1=relu(P[src]+Q'[dst]); h2=relu(h1@W2^T+b2); out=h2@w3+b3.
// 256 thr / 4 waves; wave w owns n in [w*64, w*64+64); W2 frags in registers
// (bw[4][8]=128 VGPR + acc 64 AGPR, (256,2) -> NO reg cap, no spill; 20%
// occupancy but empirically fastest: rounds 3-5 proved every reg-cap/occupancy
// trade spills and loses).
__launch_bounds__(256, 2)
__global__ void k_edge(const unsigned short* __restrict__ PQ,
                       const int* __restrict__ src, const int* __restrict__ dst,
                       const unsigned short* __restrict__ W2b,
                       const float* __restrict__ b2, const float* __restrict__ W3,
                       const float* __restrict__ b3, float* __restrict__ out,
                       int E, int ntiles) {
  __shared__ __align__(16) short smH[64 * 264];   // 33.8 KB, stride 264
  __shared__ float smS[4][64];
  const int tid = threadIdx.x;
  const int wave = tid >> 6, lane = tid & 63;
  const int lr = lane & 15, lg = lane >> 4;

  // W2 fragments (this wave's 64 N rows, full K=256): 4 n-tiles x 8 k-steps
  bfx8 bw[4][8];
  float b2v[4], w3v[4];
#pragma unroll
  for (int nt = 0; nt < 4; ++nt) {
    int n = wave * 64 + nt * 16 + lr;
    b2v[nt] = b2[n];
    w3v[nt] = W3[n];
#pragma unroll
    for (int ks = 0; ks < 8; ++ks)
      bw[nt][ks] = *(const bfx8*)(W2b + n * 256 + ks * 32 + lg * 8);
  }
  const float b3v = b3[0];

  for (int tile = blockIdx.x; tile < ntiles; tile += gridDim.x) {
    const int base = tile * E_TILE;
    // gather + fuse layer1: h1 = relu(P[src]+Q'[dst]) -> smH bf16 (b1 already in Q')
    {
      int r = tid >> 2;
      int e = base + r;
      if (e < E) {
        int s = src[e], d = dst[e];
        const unsigned short* ps = PQ + (size_t)s * 512;
        const unsigned short* pd = PQ + (size_t)d * 512 + 256;
#pragma unroll
        for (int it = 0; it < 8; ++it) {
          int c = (tid & 3) * 8 + it * 32;
          bfx8 pv = *(const bfx8*)(ps + c);
          bfx8 qv = *(const bfx8*)(pd + c);
          bfx8 o;
#pragma unroll
          for (int j = 0; j < 8; ++j)
            o[j] = f2b(relu(b2f(pv[j]) + b2f(qv[j])));
          *(bfx8*)&smH[r * 264 + c] = o;
        }
      } else {
        bfx8 z = (bfx8){0, 0, 0, 0, 0, 0, 0, 0};
#pragma unroll
        for (int it = 0; it < 8; ++it) {
          int c = (tid & 3) * 8 + it * 32;
          *(bfx8*)&smH[r * 264 + c] = z;
        }
      }
    }
    __syncthreads();

    // layer2 GEMM: 64M x 64N per wave, K=256
    fx4 acc[4][4] = {};
#pragma unroll
    for (int ks = 0; ks < 8; ++ks) {
      bfx8 af[4];
#pragma unroll
      for (int mt = 0; mt < 4; ++mt)
        af[mt] = *(const bfx8*)&smH[(mt * 16 + lr) * 264 + ks * 32 + lg * 8];
#pragma unroll
      for (int nt = 0; nt < 4; ++nt)
#pragma unroll
        for (int mt = 0; mt < 4; ++mt)
          acc[mt][nt] = __builtin_amdgcn_mfma_f32_16x16x32_bf16(af[mt], bw[nt][ks], acc[mt][nt], 0, 0, 0);
    }

    // epilogue: relu(acc+b2) dot w3, shfl-reduce over this wave's 64 n
#pragma unroll
    for (int mt = 0; mt < 4; ++mt)
#pragma unroll
      for (int i = 0; i < 4; ++i) {
        float p = 0.f;
#pragma unroll
        for (int nt = 0; nt < 4; ++nt)
          p += relu(acc[mt][nt][i] + b2v[nt]) * w3v[nt];
        p += __shfl_xor(p, 1);
        p += __shfl_xor(p, 2);
        p += __shfl_xor(p, 4);
        p += __shfl_xor(p, 8);
        if (lr == 0) smS[wave][mt * 16 + lg * 4 + i] = p;
      }
    __syncthreads();
    if (tid < 64) {
      int e = base + tid;
      if (e < E) out[e] = smS[0][tid] + smS[1][tid] + smS[2][tid] + smS[3][tid] + b3v;
    }
    __syncthreads();
  }
}

// ---------------- fallback (if ws too small): naive fp32, 1 edge per wave ----------------
__global__ void k_fallback(const float* __restrict__ x, const int* __restrict__ src,
                           const int* __restrict__ dst, const float* __restrict__ W1,
                           const float* __restrict__ b1, const float* __restrict__ W2,
                           const float* __restrict__ b2, const float* __restrict__ W3,
                           const float* __restrict__ b3, float* __restrict__ out, int E) {
  __shared__ float smF[4][512];
  __shared__ float smG[4][256];
  int wave = threadIdx.x >> 6, lane = threadIdx.x & 63;
  int e = blockIdx.x * 4 + wave;
  bool valid = e < E;
  int ec = valid ? e : 0;
  int s = src[ec], d = dst[ec];
  for (int j = 0; j < 8; ++j) {
    int k = lane * 8 + j;
    smF[wave][k] = (k < 256) ? x[(size_t)s * 256 + k] : x[(size_t)d * 256 + k - 256];
  }
  __syncthreads();
  for (int t = 0; t < 4; ++t) {
    int n = lane + t * 64;
    float a = b1[n];
    for (int k = 0; k < 512; ++k) a += smF[wave][k] * W1[n * 512 + k];
    smG[wave][n] = relu(a);
  }
  __syncthreads();
  float p = 0.f;
  for (int t = 0; t < 4; ++t) {
    int n = lane + t * 64;
    float a = b2[n];
    for (int k = 0; k < 256; ++k) a += smG[wave][k] * W2[n * 256 + k];
    p += relu(a) * W3[n];
  }
  for (int m = 1; m < 64; m <<= 1) p += __shfl_xor(p, m);
  if (lane == 0 && valid) out[e] = p + b3[0];
}

extern "C" void kernel_launch(void* const* d_in, const int* in_sizes, int n_in,
                              void* d_out, int out_size, void* d_ws, size_t ws_size,
                              hipStream_t stream) {
  const float* x  = (const float*)d_in[0];
  const int*   src = (const int*)d_in[1];
  const int*   dst = (const int*)d_in[2];
  const float* W1 = (const float*)d_in[3];
  const float* b1 = (const float*)d_in[4];
  const float* W2 = (const float*)d_in[5];
  const float* b2 = (const float*)d_in[6];
  const float* W3 = (const float*)d_in[7];
  const float* b3 = (const float*)d_in[8];
  float* out = (float*)d_out;

  const int E = in_sizes[1];
  const int n_nodes = in_sizes[0] / 256;

  const size_t offB1 = 0;
  const size_t offW2 = (size_t)512 * 256 * 2;                 // 262144
  const size_t offPQ = offW2 + (size_t)256 * 256 * 2;         // 393216
  const size_t need = offPQ + (size_t)n_nodes * 512 * 2;      // ~51.6 MB

  if (ws_size >= need) {
    unsigned short* B1  = (unsigned short*)((char*)d_ws + offB1);
    unsigned short* W2b = (unsigned short*)((char*)d_ws + offW2);
    unsigned short* PQ  = (unsigned short*)((char*)d_ws + offPQ);
    k_prep<<<768, 256, 0, stream>>>(W1, W2, B1, W2b);
    k_node<<<(n_nodes + 63) / 64, 256, 0, stream>>>(x, B1, b1, PQ, n_nodes);
    const int ntiles = (E + E_TILE - 1) / E_TILE;
    k_edge<<<512, 256, 0, stream>>>(PQ, src, dst, W2b, b2, W3, b3, out, E, ntiles);
  } else {
    k_fallback<<<(E + 3) / 4, 256, 0, stream>>>(x, src, dst, W1, b1, W2, b2, W3, b3, out, E);
  }
}